// Round 3
// baseline (114.943 us; speedup 1.0000x reference)
//
#include <hip/hip_runtime.h>
#include <hip/hip_bf16.h>

// y = x @ (W^T * S), S = sum_{k=0}^{100} (-M)^k ~= prod_{i=0}^{5} (I + A^(2^i)), A = -M
// (64 terms; ||M^64|| ~ 1e-17 << f32 eps). Chain: 6 k-parallel launches, last writes
// P transposed bf16. GEMM: B-half (128 cols x 512 k = 128 KB) resident in LDS, staged
// ONCE per block; k-loop is barrier-free (A direct global->reg, B from swizzled LDS).

typedef float f32x4 __attribute__((ext_vector_type(4)));
typedef __bf16 bf16x8 __attribute__((ext_vector_type(8)));

#define IN 512
#define OUT 256
#define BATCH 65536

#define GLOAD_LDS16(gp, lp)                                                              \
    __builtin_amdgcn_global_load_lds((const __attribute__((address_space(1))) void*)(gp), \
                                     (__attribute__((address_space(3))) void*)(lp), 16, 0, 0)

// ---------------- chain: k-parallel small matmuls (unchanged, verified) ----------------
__device__ __forceinline__ void chain_core(const float (*sA)[256], const float* __restrict__ B,
                                           int j, int q, float acc[8]) {
#pragma unroll
    for (int r = 0; r < 8; ++r) acc[r] = 0.f;
    const int kbase = q * 64;
#pragma unroll
    for (int it = 0; it < 16; ++it) {
        const int k = kbase + it * 4;
        const float b0 = B[(k + 0) * 256 + j];
        const float b1 = B[(k + 1) * 256 + j];
        const float b2 = B[(k + 2) * 256 + j];
        const float b3 = B[(k + 3) * 256 + j];
#pragma unroll
        for (int r = 0; r < 8; ++r) {
            const f32x4 av = *(const f32x4*)&sA[r][k];
            acc[r] += av[0] * b0 + av[1] * b1 + av[2] * b2 + av[3] * b3;
        }
    }
}

__global__ __launch_bounds__(1024) void nsm_chain_step(const float* __restrict__ Bmat,
                                                       const float* __restrict__ Pin,
                                                       float* __restrict__ Tout,
                                                       float* __restrict__ Pout,
                                                       const int first) {
    __shared__ float sA[8][256];
    __shared__ float ws[4][8][256];
    const int t = threadIdx.x, j = t & 255, q = t >> 8, b = blockIdx.x;
    float acc[8];
    const bool isT = (b < 32);
    if (isT) {
        const int i0 = b * 8;
        sA[2 * q][j]     = Bmat[(i0 + 2 * q) * 256 + j];
        sA[2 * q + 1][j] = Bmat[(i0 + 2 * q + 1) * 256 + j];
    } else {
        const int i0 = (b - 32) * 8;
        if (first) {
            sA[2 * q][j]     = Pin[j * IN + i0 + 2 * q];
            sA[2 * q + 1][j] = Pin[j * IN + i0 + 2 * q + 1];
        } else {
            sA[2 * q][j]     = Pin[(i0 + 2 * q) * 256 + j];
            sA[2 * q + 1][j] = Pin[(i0 + 2 * q + 1) * 256 + j];
        }
    }
    __syncthreads();
    chain_core(sA, Bmat, j, q, acc);
#pragma unroll
    for (int r = 0; r < 8; ++r) ws[q][r][j] = acc[r];
    __syncthreads();
#pragma unroll
    for (int d = 0; d < 2; ++d) {
        const int r = 2 * q + d;
        const float v = ws[0][r][j] + ws[1][r][j] + ws[2][r][j] + ws[3][r][j];
        if (isT) {
            const int i0 = b * 8;
            Tout[(i0 + r) * 256 + j] = v;
        } else {
            const int i0 = (b - 32) * 8;
            Pout[(i0 + r) * 256 + j] = first ? (sA[r][j] - v) : (sA[r][j] + v);
        }
    }
}

__global__ __launch_bounds__(1024) void nsm_chain_last(const float* __restrict__ Bmat,
                                                       const float* __restrict__ Pin,
                                                       __bf16* __restrict__ Ptb) {
    __shared__ float sA[8][256];
    __shared__ float ws[4][8][256];
    const int t = threadIdx.x, j = t & 255, q = t >> 8, b = blockIdx.x;
    const int i0 = b * 8;
    float acc[8];
    sA[2 * q][j]     = Pin[(i0 + 2 * q) * 256 + j];
    sA[2 * q + 1][j] = Pin[(i0 + 2 * q + 1) * 256 + j];
    __syncthreads();
    chain_core(sA, Bmat, j, q, acc);
#pragma unroll
    for (int r = 0; r < 8; ++r) ws[q][r][j] = acc[r];
    __syncthreads();
#pragma unroll
    for (int d = 0; d < 2; ++d) {
        const int r = 2 * q + d;
        const float v = ws[0][r][j] + ws[1][r][j] + ws[2][r][j] + ws[3][r][j];
        Ptb[(size_t)j * IN + i0 + r] = (__bf16)(sA[r][j] + v);
    }
}

// ---------------- big GEMM: y[65536][256] = x[65536][512] @ P ----------------
// Grid 512 = (m-chunk 0..255) x (n-half 0..1), paired so (m,0)/(m,1) are adjacent
// (co-resident -> x HBM lines fetched once, twin hits L2/L3).
// Block: 512 thr = 8 waves (4M x 2N), wave tile 64 rows x 64 cols; block 256 x 128.
// LDS: pb[128 local cols][512 k] bf16 = 128 KB, staged ONCE (source-swizzled so the
// linear global_load_lds dest + XOR'd ds_read give ~2-way banks = free). K-loop has
// NO barriers: A-frags stream global->reg (depth-2 prefetch), B-frags from LDS.
__global__ __launch_bounds__(512, 2) void nsm_gemm_xP(const float* __restrict__ x,
                                                      const __bf16* __restrict__ Pt,
                                                      float* __restrict__ y) {
    __shared__ __bf16 pb[128][512];  // 128 KB
    const int tid = threadIdx.x;
    const int wave = tid >> 6, lane = tid & 63;
    const int l15 = lane & 15, lhi = lane >> 4;
    const int wm = wave >> 1, wn = wave & 1;
    const int mb = blockIdx.x >> 1;
    const int nh = blockIdx.x & 1;
    const int m0 = mb * 256 + wm * 64;
    const int nc0 = nh * 128;

    // ---- stage B-half once: col-row = 1 KB = one gload_lds call (64 lanes x 16 B).
    // LDS slot l holds global 16B-chunk (l ^ (col&7)); read applies the same XOR.
#pragma unroll
    for (int i = 0; i < 16; ++i) {
        const int coll = wave * 16 + i;
        const __bf16* src = Pt + (size_t)(nc0 + coll) * IN + ((lane ^ (coll & 7)) << 3);
        GLOAD_LDS16(src, &pb[coll][0]);
    }

    f32x4 acc[4][4];
#pragma unroll
    for (int a = 0; a < 4; ++a)
#pragma unroll
        for (int c = 0; c < 4; ++c) acc[a][c] = (f32x4){0.f, 0.f, 0.f, 0.f};

    __syncthreads();  // pb ready (compiler drains vmcnt before barrier)

    // A row base pointers (offsets within k fold into the 13-bit imm)
    const float* px[4];
#pragma unroll
    for (int mt = 0; mt < 4; ++mt)
        px[mt] = x + (size_t)(m0 + mt * 16 + l15) * IN + lhi * 8;

    f32x4 xa[2][4][2];
#pragma unroll
    for (int mt = 0; mt < 4; ++mt) {
        xa[0][mt][0] = *(const f32x4*)(px[mt]);
        xa[0][mt][1] = *(const f32x4*)(px[mt] + 4);
    }

#pragma unroll
    for (int ks = 0; ks < 16; ++ks) {
        const int cur = ks & 1;  // static after full unroll
        if (ks < 15) {
#pragma unroll
            for (int mt = 0; mt < 4; ++mt) {
                xa[cur ^ 1][mt][0] = *(const f32x4*)(px[mt] + (ks + 1) * 32);
                xa[cur ^ 1][mt][1] = *(const f32x4*)(px[mt] + (ks + 1) * 32 + 4);
            }
        }
        bf16x8 bfr[4];
#pragma unroll
        for (int nt = 0; nt < 4; ++nt) {
            const int coll = wn * 64 + nt * 16 + l15;
            const int slot = (ks * 4 + lhi) ^ (coll & 7);
            bfr[nt] = *(const bf16x8*)&pb[coll][slot << 3];
        }
        bf16x8 af[4];
#pragma unroll
        for (int mt = 0; mt < 4; ++mt) {
            bf16x8 t;
            t[0] = (__bf16)xa[cur][mt][0][0]; t[1] = (__bf16)xa[cur][mt][0][1];
            t[2] = (__bf16)xa[cur][mt][0][2]; t[3] = (__bf16)xa[cur][mt][0][3];
            t[4] = (__bf16)xa[cur][mt][1][0]; t[5] = (__bf16)xa[cur][mt][1][1];
            t[6] = (__bf16)xa[cur][mt][1][2]; t[7] = (__bf16)xa[cur][mt][1][3];
            af[mt] = t;
        }
#pragma unroll
        for (int mt = 0; mt < 4; ++mt)
#pragma unroll
            for (int nt = 0; nt < 4; ++nt)
                acc[mt][nt] = __builtin_amdgcn_mfma_f32_16x16x32_bf16(af[mt], bfr[nt], acc[mt][nt], 0, 0, 0);
    }

#pragma unroll
    for (int mt = 0; mt < 4; ++mt) {
#pragma unroll
        for (int nt = 0; nt < 4; ++nt) {
            const int col = nc0 + wn * 64 + nt * 16 + l15;
            const int row = m0 + mt * 16 + lhi * 4;
#pragma unroll
            for (int r = 0; r < 4; ++r) y[(size_t)(row + r) * OUT + col] = acc[mt][nt][r];
        }
    }
}

extern "C" void kernel_launch(void* const* d_in, const int* in_sizes, int n_in,
                              void* d_out, int out_size, void* d_ws, size_t ws_size,
                              hipStream_t stream) {
    const float* x = (const float*)d_in[0];   // [65536][512]
    const float* W = (const float*)d_in[1];   // [256][512]
    const float* M = (const float*)d_in[2];   // [256][256]
    float* y = (float*)d_out;                 // [65536][256]

    char* ws = (char*)d_ws;
    float* Ta = (float*)(ws);                   // 256 KB
    float* Tb = (float*)(ws + (256 << 10));     // 256 KB
    float* Pa = (float*)(ws + (512 << 10));     // 512 KB
    float* Pb = (float*)(ws + (1024 << 10));    // 512 KB
    __bf16* Ptb = (__bf16*)(ws + (1536 << 10)); // 256 KB  bf16 [256][512]

    nsm_chain_step<<<96, 1024, 0, stream>>>(M, W, Ta, Pa, 1);   // T1=A^2, P0=W^T(I+A)
    nsm_chain_step<<<96, 1024, 0, stream>>>(Ta, Pa, Tb, Pb, 0); // T2=A^4,  P1
    nsm_chain_step<<<96, 1024, 0, stream>>>(Tb, Pb, Ta, Pa, 0); // T3=A^8,  P2
    nsm_chain_step<<<96, 1024, 0, stream>>>(Ta, Pa, Tb, Pb, 0); // T4=A^16, P3
    nsm_chain_step<<<96, 1024, 0, stream>>>(Tb, Pb, Ta, Pa, 0); // T5=A^32, P4
    nsm_chain_last<<<64, 1024, 0, stream>>>(Ta, Pa, Ptb);       // Ptb = bf16(P5^T)
    nsm_gemm_xP<<<512, 512, 0, stream>>>(x, Ptb, y);            // y = x @ P
}